// Round 3
// baseline (640.867 us; speedup 1.0000x reference)
//
#include <hip/hip_runtime.h>
#include <hip/hip_bf16.h>

#define N_NODES 8192
#define N_EDGES 262144
#define IN_DIM  512
#define HID     256
#define EMB     64
#define C2      128   // 2*EMB concat width

// ---------------- CSR build ----------------
__global__ __launch_bounds__(256) void k_count(const int* __restrict__ dst, int* __restrict__ deg) {
    int e = blockIdx.x * 256 + threadIdx.x;   // grid exactly covers E
    atomicAdd(&deg[dst[e]], 1);
}

__global__ __launch_bounds__(1024) void k_scan(const int* __restrict__ deg, int* __restrict__ rowptr) {
    __shared__ int part[1024];
    const int t = threadIdx.x;
    const int base = t * 8;
    int v[8], incl[8];
    int s = 0;
    #pragma unroll
    for (int j = 0; j < 8; ++j) { v[j] = deg[base + j]; s += v[j]; incl[j] = s; }
    part[t] = s;
    __syncthreads();
    for (int off = 1; off < 1024; off <<= 1) {
        int x = (t >= off) ? part[t - off] : 0;
        __syncthreads();
        part[t] += x;
        __syncthreads();
    }
    int excl = part[t] - s;
    if (t == 0) rowptr[0] = 0;
    #pragma unroll
    for (int j = 0; j < 8; ++j) rowptr[base + j + 1] = excl + incl[j];
}

__global__ __launch_bounds__(256) void k_fill(const int* __restrict__ src, const int* __restrict__ dst,
                                              const float* __restrict__ ew, const int* __restrict__ rowptr,
                                              int* __restrict__ cursor, int* __restrict__ srcs,
                                              float* __restrict__ wsorted) {
    int e = blockIdx.x * 256 + threadIdx.x;
    int d = dst[e];
    int p = rowptr[d] + atomicAdd(&cursor[d], 1);
    srcs[p] = src[e];
    wsorted[p] = ew[e];
}

// ---------------- Wc = W0 @ [Wm | Wl], stored transposed: WcT[j][k], j<128, k<512 ----------------
__global__ __launch_bounds__(256) void k_wc(const float* __restrict__ W0, const float* __restrict__ Wm,
                                            const float* __restrict__ Wl, float* __restrict__ WcT) {
    __shared__ float w0s[16][256];            // 16 k-rows of W0
    const int t = threadIdx.x;
    const int kb = blockIdx.x * 16;
    #pragma unroll
    for (int m = 0; m < 4; ++m) {
        int f = t + 256 * m;                  // 0..1023 float4 slots (16*256/4)
        int row = f >> 6, q = f & 63;
        *(float4*)&w0s[row][q * 4] = *(const float4*)&W0[(size_t)(kb + row) * 256 + q * 4];
    }
    __syncthreads();
    const int j = t & 127, kh = t >> 7;       // col, k-half (8 rows each)
    const float* B = (j < 64) ? (Wm + j) : (Wl + (j - 64));   // wave-uniform branch
    float acc[8] = {};
    for (int h = 0; h < 256; h += 4) {
        float b0 = B[(h + 0) * 64], b1 = B[(h + 1) * 64];
        float b2 = B[(h + 2) * 64], b3 = B[(h + 3) * 64];
        #pragma unroll
        for (int r = 0; r < 8; ++r) {
            float4 x = *(const float4*)&w0s[kh * 8 + r][h];
            acc[r] += x.x * b0 + x.y * b1 + x.z * b2 + x.w * b3;
        }
    }
    #pragma unroll
    for (int r = 0; r < 8; ++r)
        WcT[(size_t)j * 512 + kb + kh * 8 + r] = acc[r];
}

// ---------------- P = X @ Wc  [8192 x 128] ----------------
__global__ __launch_bounds__(256) void k_gemm_p(const float* __restrict__ X, const float* __restrict__ WcT,
                                                float* __restrict__ P) {
    __shared__ float Xs[32][68];              // 32 rows x 64-k chunk, padded
    const int t = threadIdx.x;
    const int i0 = blockIdx.x * 32;
    const int rg = t >> 6, cpair = t & 63, c0 = cpair * 2;
    float acc[8][2] = {};
    for (int kc = 0; kc < 512; kc += 64) {
        #pragma unroll
        for (int m = 0; m < 2; ++m) {
            int f = t + 256 * m;              // 0..511 float4 slots (32*64/4)
            int row = f >> 4, q = f & 15;
            *(float4*)&Xs[row][q * 4] = *(const float4*)&X[(size_t)(i0 + row) * 512 + kc + q * 4];
        }
        __syncthreads();
        #pragma unroll 4
        for (int k4 = 0; k4 < 16; ++k4) {
            float4 wA = *(const float4*)&WcT[(size_t)c0 * 512 + kc + k4 * 4];
            float4 wB = *(const float4*)&WcT[(size_t)(c0 + 1) * 512 + kc + k4 * 4];
            #pragma unroll
            for (int r = 0; r < 8; ++r) {
                float4 x = *(const float4*)&Xs[rg * 8 + r][k4 * 4];
                acc[r][0] += x.x * wA.x + x.y * wA.y + x.z * wA.z + x.w * wA.w;
                acc[r][1] += x.x * wB.x + x.y * wB.y + x.z * wB.z + x.w * wB.w;
            }
        }
        __syncthreads();
    }
    #pragma unroll
    for (int r = 0; r < 8; ++r) {
        float2 v = make_float2(acc[r][0], acc[r][1]);
        *(float2*)&P[(size_t)(i0 + rg * 8 + r) * 128 + c0] = v;
    }
}

// ---------------- aggregate: Out[d] = sum_{e: dst=d} In[src(e)] * w(e); optional Z epilogue ----------------
__global__ __launch_bounds__(128) void k_agg(const float* __restrict__ In, const int* __restrict__ rowptr,
                                             const int* __restrict__ srcs, const float* __restrict__ wsorted,
                                             float* __restrict__ Out, const float* __restrict__ noise,
                                             float* __restrict__ Z, int zpass) {
    const int b = blockIdx.x, t = threadIdx.x;
    const int beg = rowptr[b], end = rowptr[b + 1];
    float a0 = 0.f, a1 = 0.f, a2 = 0.f, a3 = 0.f;
    int i = beg;
    for (; i + 4 <= end; i += 4) {
        int   s0 = srcs[i],     s1 = srcs[i + 1], s2 = srcs[i + 2], s3 = srcs[i + 3];
        float w0 = wsorted[i],  w1 = wsorted[i + 1], w2 = wsorted[i + 2], w3 = wsorted[i + 3];
        a0 += In[(size_t)s0 * C2 + t] * w0;
        a1 += In[(size_t)s1 * C2 + t] * w1;
        a2 += In[(size_t)s2 * C2 + t] * w2;
        a3 += In[(size_t)s3 * C2 + t] * w3;
    }
    for (; i < end; ++i)
        a0 += In[(size_t)srcs[i] * C2 + t] * wsorted[i];
    float acc = (a0 + a1) + (a2 + a3);
    if (!zpass) {
        Out[(size_t)b * C2 + t] = acc;
    } else {
        __shared__ float u[C2];
        u[t] = acc;
        __syncthreads();
        if (t < 64) {
            float m = fmaxf(u[t], 0.f);
            float l = fmaxf(u[t + 64], 0.f);
            // clamp so Z is finite and a 64-term dot cannot exceed FLT_MAX:
            // |z| <= 1e18 -> |dot| <= 64 * 1e36 = 6.4e37 < 3.4e38
            float z = noise[(size_t)b * 64 + t] * expf(fminf(l, 80.f)) + m;
            z = fminf(fmaxf(z, -1e18f), 1e18f);
            Z[(size_t)b * 64 + t] = z;
        }
    }
}

// ---------------- out = Z @ Z^T  [8192 x 8192], symmetric, 128x128 tiles, 8x8 acc, NO LDS ----------------
// Z (2 MB) is L2/L3-resident; fragments come straight from global. 16 dwordx4 loads feed 256 FMA
// per 4-k chunk (16 FMA/load). No __syncthreads, no bank conflicts, no LDS occupancy cliff.
// Column/row ownership is {tx*4, 64+tx*4} so every float4 store is part of a 256B-contiguous row segment.
__global__ __launch_bounds__(256) void k_zzt(const float* __restrict__ Z, float* __restrict__ out) {
    if (blockIdx.x < blockIdx.y) return;      // upper triangle of 128x128 tiles: j0 >= i0
    const int t = threadIdx.x;
    const int tx = t & 15, ty = t >> 4;
    const int i0 = blockIdx.y * 128, j0 = blockIdx.x * 128;
    // thread's rows: i0 + rg*64 + ty*4 + r ; cols: j0 + cg*64 + tx*4 + c   (rg,cg in {0,1}; r,c in 0..3)
    const float* A0 = Z + (size_t)(i0 + ty * 4) * 64;
    const float* A1 = Z + (size_t)(i0 + 64 + ty * 4) * 64;
    const float* B0 = Z + (size_t)(j0 + tx * 4) * 64;
    const float* B1 = Z + (size_t)(j0 + 64 + tx * 4) * 64;
    float acc[2][4][2][4] = {};
    for (int k = 0; k < 64; k += 4) {
        float4 a[2][4], b[2][4];
        #pragma unroll
        for (int r = 0; r < 4; ++r) {
            a[0][r] = *(const float4*)&A0[r * 64 + k];
            a[1][r] = *(const float4*)&A1[r * 64 + k];
            b[0][r] = *(const float4*)&B0[r * 64 + k];
            b[1][r] = *(const float4*)&B1[r * 64 + k];
        }
        #pragma unroll
        for (int rg = 0; rg < 2; ++rg)
            #pragma unroll
            for (int r = 0; r < 4; ++r)
                #pragma unroll
                for (int cg = 0; cg < 2; ++cg)
                    #pragma unroll
                    for (int c = 0; c < 4; ++c)
                        acc[rg][r][cg][c] += a[rg][r].x * b[cg][c].x + a[rg][r].y * b[cg][c].y
                                           + a[rg][r].z * b[cg][c].z + a[rg][r].w * b[cg][c].w;
    }
    // direct tile (i0, j0): per instr, 4 rows x 16 tx x 16B = 256B-contiguous row segments
    #pragma unroll
    for (int rg = 0; rg < 2; ++rg)
        #pragma unroll
        for (int r = 0; r < 4; ++r) {
            size_t row = (size_t)(i0 + rg * 64 + ty * 4 + r);
            #pragma unroll
            for (int cg = 0; cg < 2; ++cg) {
                float4 v = make_float4(acc[rg][r][cg][0], acc[rg][r][cg][1],
                                       acc[rg][r][cg][2], acc[rg][r][cg][3]);
                *(float4*)&out[row * N_NODES + j0 + cg * 64 + tx * 4] = v;
            }
        }
    // mirrored tile (j0, i0): transposed straight from registers; 4 ty-lanes form 64B-contiguous segments
    if (i0 != j0) {
        #pragma unroll
        for (int cg = 0; cg < 2; ++cg)
            #pragma unroll
            for (int c = 0; c < 4; ++c) {
                size_t row = (size_t)(j0 + cg * 64 + tx * 4 + c);
                #pragma unroll
                for (int rg = 0; rg < 2; ++rg) {
                    float4 v = make_float4(acc[rg][0][cg][c], acc[rg][1][cg][c],
                                           acc[rg][2][cg][c], acc[rg][3][cg][c]);
                    *(float4*)&out[row * N_NODES + i0 + rg * 64 + ty * 4] = v;
                }
            }
    }
}

extern "C" void kernel_launch(void* const* d_in, const int* in_sizes, int n_in,
                              void* d_out, int out_size, void* d_ws, size_t ws_size,
                              hipStream_t stream) {
    const float* X     = (const float*)d_in[0];
    const int*   ei    = (const int*)d_in[1];
    const float* ew    = (const float*)d_in[2];
    const float* W0    = (const float*)d_in[3];
    const float* Wm    = (const float*)d_in[4];
    const float* Wl    = (const float*)d_in[5];
    const float* noise = (const float*)d_in[6];
    float* out = (float*)d_out;

    const int* srcI = ei;                 // edge_index[0]
    const int* dstI = ei + N_EDGES;       // edge_index[1]

    // workspace layout, all in d_ws (~12.9 MB)
    int*   deg     = (int*)d_ws;                          // 8192
    int*   cursor  = deg + 8192;                          // 8192
    int*   rowptr  = deg + 16384;                         // 8193 (pad to 24592)
    int*   srcs    = deg + 24592;                         // E
    float* wsorted = (float*)(deg + 24592 + N_EDGES);     // E
    float* WcT     = wsorted + N_EDGES;                   // 128*512
    float* P       = WcT + 128 * 512;                     // 8192*128
    float* U1      = P + (size_t)N_NODES * C2;            // 8192*128
    float* Z       = U1 + (size_t)N_NODES * C2;           // 8192*64

    hipMemsetAsync(deg, 0, 16384 * sizeof(int), stream);  // deg + cursor

    k_count<<<N_EDGES / 256, 256, 0, stream>>>(dstI, deg);
    k_scan<<<1, 1024, 0, stream>>>(deg, rowptr);
    k_fill<<<N_EDGES / 256, 256, 0, stream>>>(srcI, dstI, ew, rowptr, cursor, srcs, wsorted);
    k_wc<<<32, 256, 0, stream>>>(W0, Wm, Wl, WcT);
    k_gemm_p<<<N_NODES / 32, 256, 0, stream>>>(X, WcT, P);
    k_agg<<<N_NODES, 128, 0, stream>>>(P, rowptr, srcs, wsorted, U1, nullptr, nullptr, 0);
    k_agg<<<N_NODES, 128, 0, stream>>>(U1, rowptr, srcs, wsorted, nullptr, noise, Z, 1);
    k_zzt<<<dim3(N_NODES / 128, N_NODES / 128), 256, 0, stream>>>(Z, out);
}

// Round 4
// 521.958 us; speedup vs baseline: 1.2278x; 1.2278x over previous
//
#include <hip/hip_runtime.h>
#include <hip/hip_bf16.h>

#define N_NODES 8192
#define N_EDGES 262144
#define IN_DIM  512
#define HID     256
#define EMB     64
#define C2      128   // 2*EMB concat width

// ---------------- CSR build ----------------
__global__ __launch_bounds__(256) void k_count(const int* __restrict__ dst, int* __restrict__ deg) {
    int e = blockIdx.x * 256 + threadIdx.x;   // grid exactly covers E
    atomicAdd(&deg[dst[e]], 1);
}

__global__ __launch_bounds__(1024) void k_scan(const int* __restrict__ deg, int* __restrict__ rowptr) {
    __shared__ int part[1024];
    const int t = threadIdx.x;
    const int base = t * 8;
    int v[8], incl[8];
    int s = 0;
    #pragma unroll
    for (int j = 0; j < 8; ++j) { v[j] = deg[base + j]; s += v[j]; incl[j] = s; }
    part[t] = s;
    __syncthreads();
    for (int off = 1; off < 1024; off <<= 1) {
        int x = (t >= off) ? part[t - off] : 0;
        __syncthreads();
        part[t] += x;
        __syncthreads();
    }
    int excl = part[t] - s;
    if (t == 0) rowptr[0] = 0;
    #pragma unroll
    for (int j = 0; j < 8; ++j) rowptr[base + j + 1] = excl + incl[j];
}

__global__ __launch_bounds__(256) void k_fill(const int* __restrict__ src, const int* __restrict__ dst,
                                              const float* __restrict__ ew, const int* __restrict__ rowptr,
                                              int* __restrict__ cursor, int* __restrict__ srcs,
                                              float* __restrict__ wsorted) {
    int e = blockIdx.x * 256 + threadIdx.x;
    int d = dst[e];
    int p = rowptr[d] + atomicAdd(&cursor[d], 1);
    srcs[p] = src[e];
    wsorted[p] = ew[e];
}

// ---------------- Wc = W0 @ [Wm | Wl], stored transposed: WcT[j][k], j<128, k<512 ----------------
__global__ __launch_bounds__(256) void k_wc(const float* __restrict__ W0, const float* __restrict__ Wm,
                                            const float* __restrict__ Wl, float* __restrict__ WcT) {
    __shared__ float w0s[16][256];            // 16 k-rows of W0
    const int t = threadIdx.x;
    const int kb = blockIdx.x * 16;
    #pragma unroll
    for (int m = 0; m < 4; ++m) {
        int f = t + 256 * m;                  // 0..1023 float4 slots (16*256/4)
        int row = f >> 6, q = f & 63;
        *(float4*)&w0s[row][q * 4] = *(const float4*)&W0[(size_t)(kb + row) * 256 + q * 4];
    }
    __syncthreads();
    const int j = t & 127, kh = t >> 7;       // col, k-half (8 rows each)
    const float* B = (j < 64) ? (Wm + j) : (Wl + (j - 64));   // wave-uniform branch
    float acc[8] = {};
    for (int h = 0; h < 256; h += 4) {
        float b0 = B[(h + 0) * 64], b1 = B[(h + 1) * 64];
        float b2 = B[(h + 2) * 64], b3 = B[(h + 3) * 64];
        #pragma unroll
        for (int r = 0; r < 8; ++r) {
            float4 x = *(const float4*)&w0s[kh * 8 + r][h];
            acc[r] += x.x * b0 + x.y * b1 + x.z * b2 + x.w * b3;
        }
    }
    #pragma unroll
    for (int r = 0; r < 8; ++r)
        WcT[(size_t)j * 512 + kb + kh * 8 + r] = acc[r];
}

// ---------------- P = X @ Wc  [8192 x 128] ----------------
__global__ __launch_bounds__(256) void k_gemm_p(const float* __restrict__ X, const float* __restrict__ WcT,
                                                float* __restrict__ P) {
    __shared__ float Xs[32][68];              // 32 rows x 64-k chunk, padded
    const int t = threadIdx.x;
    const int i0 = blockIdx.x * 32;
    const int rg = t >> 6, cpair = t & 63, c0 = cpair * 2;
    float acc[8][2] = {};
    for (int kc = 0; kc < 512; kc += 64) {
        #pragma unroll
        for (int m = 0; m < 2; ++m) {
            int f = t + 256 * m;              // 0..511 float4 slots (32*64/4)
            int row = f >> 4, q = f & 15;
            *(float4*)&Xs[row][q * 4] = *(const float4*)&X[(size_t)(i0 + row) * 512 + kc + q * 4];
        }
        __syncthreads();
        #pragma unroll 4
        for (int k4 = 0; k4 < 16; ++k4) {
            float4 wA = *(const float4*)&WcT[(size_t)c0 * 512 + kc + k4 * 4];
            float4 wB = *(const float4*)&WcT[(size_t)(c0 + 1) * 512 + kc + k4 * 4];
            #pragma unroll
            for (int r = 0; r < 8; ++r) {
                float4 x = *(const float4*)&Xs[rg * 8 + r][k4 * 4];
                acc[r][0] += x.x * wA.x + x.y * wA.y + x.z * wA.z + x.w * wA.w;
                acc[r][1] += x.x * wB.x + x.y * wB.y + x.z * wB.z + x.w * wB.w;
            }
        }
        __syncthreads();
    }
    #pragma unroll
    for (int r = 0; r < 8; ++r) {
        float2 v = make_float2(acc[r][0], acc[r][1]);
        *(float2*)&P[(size_t)(i0 + rg * 8 + r) * 128 + c0] = v;
    }
}

// ---------------- aggregate: Out[d] = sum_{e: dst=d} In[src(e)] * w(e); optional Z epilogue ----------------
__global__ __launch_bounds__(128) void k_agg(const float* __restrict__ In, const int* __restrict__ rowptr,
                                             const int* __restrict__ srcs, const float* __restrict__ wsorted,
                                             float* __restrict__ Out, const float* __restrict__ noise,
                                             float* __restrict__ Z, int zpass) {
    const int b = blockIdx.x, t = threadIdx.x;
    const int beg = rowptr[b], end = rowptr[b + 1];
    float a0 = 0.f, a1 = 0.f, a2 = 0.f, a3 = 0.f;
    int i = beg;
    for (; i + 4 <= end; i += 4) {
        int   s0 = srcs[i],     s1 = srcs[i + 1], s2 = srcs[i + 2], s3 = srcs[i + 3];
        float w0 = wsorted[i],  w1 = wsorted[i + 1], w2 = wsorted[i + 2], w3 = wsorted[i + 3];
        a0 += In[(size_t)s0 * C2 + t] * w0;
        a1 += In[(size_t)s1 * C2 + t] * w1;
        a2 += In[(size_t)s2 * C2 + t] * w2;
        a3 += In[(size_t)s3 * C2 + t] * w3;
    }
    for (; i < end; ++i)
        a0 += In[(size_t)srcs[i] * C2 + t] * wsorted[i];
    float acc = (a0 + a1) + (a2 + a3);
    if (!zpass) {
        Out[(size_t)b * C2 + t] = acc;
    } else {
        __shared__ float u[C2];
        u[t] = acc;
        __syncthreads();
        if (t < 64) {
            float m = fmaxf(u[t], 0.f);
            float l = fmaxf(u[t + 64], 0.f);
            // clamp so Z is finite and a 64-term dot cannot exceed FLT_MAX:
            // |z| <= 1e18 -> |dot| <= 64 * 1e36 = 6.4e37 < 3.4e38
            float z = noise[(size_t)b * 64 + t] * expf(fminf(l, 80.f)) + m;
            z = fminf(fmaxf(z, -1e18f), 1e18f);
            Z[(size_t)b * 64 + t] = z;
        }
    }
}

// ---------------- out = Z @ Z^T  [8192 x 8192], symmetric, 128x128 tiles, 8x8 acc ----------------
// Hybrid operand feed (R3 post-mortem): A-fragments from global (ty-broadcast, 1-4 lines/instr, fine);
// B-tile staged in 32 KB LDS, [row][k] layout, T2 XOR-swizzle on the k index:
//   store  S[row][(q*4) ^ ((row>>3 & 7)<<2)]   -> 2-way banks (free)
//   read   S[row_b][k0 ^ ((tx>>1 & 7)<<2)]     -> 2-way banks (free), b128 both ways
// No sync in the k-loop; 2 LDS reads per 64 FMAs.
__global__ __launch_bounds__(256) void k_zzt(const float* __restrict__ Z, float* __restrict__ out) {
    if (blockIdx.x < blockIdx.y) return;      // upper triangle of 128x128 tiles: j0 >= i0
    __shared__ float S[128][64];              // 32 KB B-slab, k-swizzled
    const int t = threadIdx.x;
    const int tx = t & 15, ty = t >> 4;
    const int i0 = blockIdx.y * 128, j0 = blockIdx.x * 128;
    // stage B rows j0..j0+127 (each row = 64 floats = 256B, fully coalesced)
    #pragma unroll
    for (int m = 0; m < 8; ++m) {
        int f = t + 256 * m;                  // 0..2047 float4 slots (128 rows x 16)
        int row = f >> 4, q = f & 15;
        float4 v = *(const float4*)&Z[(size_t)(j0 + row) * 64 + q * 4];
        *(float4*)&S[row][(q * 4) ^ ((row >> 3 & 7) << 2)] = v;
    }
    const float* A0 = Z + (size_t)(i0 + ty * 4) * 64;        // rows i0 + ty*4 + r
    const float* A1 = Z + (size_t)(i0 + 64 + ty * 4) * 64;   // rows i0 + 64 + ty*4 + r
    const int rb0 = tx * 4, rb1 = 64 + tx * 4;               // B rows owned by this thread
    const int swz = ((tx >> 1) & 7) << 2;                    // read-side swizzle (lane-const)
    __syncthreads();
    float acc[2][4][2][4] = {};
    for (int k = 0; k < 64; k += 4) {
        const int ks = k ^ swz;
        float4 a[2][4], b[2][4];
        #pragma unroll
        for (int r = 0; r < 4; ++r) {
            a[0][r] = *(const float4*)&A0[r * 64 + k];
            a[1][r] = *(const float4*)&A1[r * 64 + k];
            b[0][r] = *(const float4*)&S[rb0 + r][ks];
            b[1][r] = *(const float4*)&S[rb1 + r][ks];
        }
        #pragma unroll
        for (int rg = 0; rg < 2; ++rg)
            #pragma unroll
            for (int r = 0; r < 4; ++r)
                #pragma unroll
                for (int cg = 0; cg < 2; ++cg)
                    #pragma unroll
                    for (int c = 0; c < 4; ++c)
                        acc[rg][r][cg][c] += a[rg][r].x * b[cg][c].x + a[rg][r].y * b[cg][c].y
                                           + a[rg][r].z * b[cg][c].z + a[rg][r].w * b[cg][c].w;
    }
    // direct tile (i0, j0): per instr, 16 tx x 16B = 256B-contiguous row segments
    #pragma unroll
    for (int rg = 0; rg < 2; ++rg)
        #pragma unroll
        for (int r = 0; r < 4; ++r) {
            size_t row = (size_t)(i0 + rg * 64 + ty * 4 + r);
            #pragma unroll
            for (int cg = 0; cg < 2; ++cg) {
                float4 v = make_float4(acc[rg][r][cg][0], acc[rg][r][cg][1],
                                       acc[rg][r][cg][2], acc[rg][r][cg][3]);
                *(float4*)&out[row * N_NODES + j0 + cg * 64 + tx * 4] = v;
            }
        }
    // mirrored tile (j0, i0): transposed straight from registers; 4 ty-lanes form 64B segments
    if (i0 != j0) {
        #pragma unroll
        for (int cg = 0; cg < 2; ++cg)
            #pragma unroll
            for (int c = 0; c < 4; ++c) {
                size_t row = (size_t)(j0 + cg * 64 + tx * 4 + c);
                #pragma unroll
                for (int rg = 0; rg < 2; ++rg) {
                    float4 v = make_float4(acc[rg][0][cg][c], acc[rg][1][cg][c],
                                           acc[rg][2][cg][c], acc[rg][3][cg][c]);
                    *(float4*)&out[row * N_NODES + i0 + rg * 64 + ty * 4] = v;
                }
            }
    }
}

extern "C" void kernel_launch(void* const* d_in, const int* in_sizes, int n_in,
                              void* d_out, int out_size, void* d_ws, size_t ws_size,
                              hipStream_t stream) {
    const float* X     = (const float*)d_in[0];
    const int*   ei    = (const int*)d_in[1];
    const float* ew    = (const float*)d_in[2];
    const float* W0    = (const float*)d_in[3];
    const float* Wm    = (const float*)d_in[4];
    const float* Wl    = (const float*)d_in[5];
    const float* noise = (const float*)d_in[6];
    float* out = (float*)d_out;

    const int* srcI = ei;                 // edge_index[0]
    const int* dstI = ei + N_EDGES;       // edge_index[1]

    // workspace layout, all in d_ws (~12.9 MB)
    int*   deg     = (int*)d_ws;                          // 8192
    int*   cursor  = deg + 8192;                          // 8192
    int*   rowptr  = deg + 16384;                         // 8193 (pad to 24592)
    int*   srcs    = deg + 24592;                         // E
    float* wsorted = (float*)(deg + 24592 + N_EDGES);     // E
    float* WcT     = wsorted + N_EDGES;                   // 128*512
    float* P       = WcT + 128 * 512;                     // 8192*128
    float* U1      = P + (size_t)N_NODES * C2;            // 8192*128
    float* Z       = U1 + (size_t)N_NODES * C2;           // 8192*64

    hipMemsetAsync(deg, 0, 16384 * sizeof(int), stream);  // deg + cursor

    k_count<<<N_EDGES / 256, 256, 0, stream>>>(dstI, deg);
    k_scan<<<1, 1024, 0, stream>>>(deg, rowptr);
    k_fill<<<N_EDGES / 256, 256, 0, stream>>>(srcI, dstI, ew, rowptr, cursor, srcs, wsorted);
    k_wc<<<32, 256, 0, stream>>>(W0, Wm, Wl, WcT);
    k_gemm_p<<<N_NODES / 32, 256, 0, stream>>>(X, WcT, P);
    k_agg<<<N_NODES, 128, 0, stream>>>(P, rowptr, srcs, wsorted, U1, nullptr, nullptr, 0);
    k_agg<<<N_NODES, 128, 0, stream>>>(U1, rowptr, srcs, wsorted, nullptr, noise, Z, 1);
    k_zzt<<<dim3(N_NODES / 128, N_NODES / 128), 256, 0, stream>>>(Z, out);
}

// Round 6
// 459.140 us; speedup vs baseline: 1.3958x; 1.1368x over previous
//
#include <hip/hip_runtime.h>
#include <hip/hip_bf16.h>

#define N_NODES 8192
#define N_EDGES 262144
#define IN_DIM  512
#define HID     256
#define EMB     64
#define C2      128   // 2*EMB concat width

// ---------------- FUSED: edge-count (blocks 0..1023) + Wc GEMM (blocks 1024..1055) ----------------
// Independent chains share one dispatch; wc's 32 blocks hide under count's atomic traffic.
__global__ __launch_bounds__(256) void k_count_wc(const int* __restrict__ dst, int* __restrict__ deg,
                                                  const float* __restrict__ W0, const float* __restrict__ Wm,
                                                  const float* __restrict__ Wl, float* __restrict__ WcT) {
    __shared__ float w0s[16][256];            // used by wc path only
    const int t = threadIdx.x;
    if (blockIdx.x < 1024) {                  // ---- count path ----
        int e = blockIdx.x * 256 + t;         // grid exactly covers E
        atomicAdd(&deg[dst[e]], 1);
        return;
    }
    // ---- Wc = W0 @ [Wm | Wl], stored transposed: WcT[j][k], j<128, k<512 ----
    const int kb = (blockIdx.x - 1024) * 16;
    #pragma unroll
    for (int m = 0; m < 4; ++m) {
        int f = t + 256 * m;                  // 0..1023 float4 slots (16*256/4)
        int row = f >> 6, q = f & 63;
        *(float4*)&w0s[row][q * 4] = *(const float4*)&W0[(size_t)(kb + row) * 256 + q * 4];
    }
    __syncthreads();
    const int j = t & 127, kh = t >> 7;       // col, k-half (8 rows each)
    const float* B = (j < 64) ? (Wm + j) : (Wl + (j - 64));   // wave-uniform branch
    float acc[8] = {};
    for (int h = 0; h < 256; h += 4) {
        float b0 = B[(h + 0) * 64], b1 = B[(h + 1) * 64];
        float b2 = B[(h + 2) * 64], b3 = B[(h + 3) * 64];
        #pragma unroll
        for (int r = 0; r < 8; ++r) {
            float4 x = *(const float4*)&w0s[kh * 8 + r][h];
            acc[r] += x.x * b0 + x.y * b1 + x.z * b2 + x.w * b3;
        }
    }
    #pragma unroll
    for (int r = 0; r < 8; ++r)
        WcT[(size_t)j * 512 + kb + kh * 8 + r] = acc[r];
}

// ---------------- FUSED: P = X @ Wc (blocks 0..255) + rowptr scan (block 256) ----------------
// The single-CU scan hides under the 256 GEMM blocks instead of idling the chip.
__global__ __launch_bounds__(256) void k_scan_gemm(const int* __restrict__ deg, int* __restrict__ rowptr,
                                                   const float* __restrict__ X, const float* __restrict__ WcT,
                                                   float* __restrict__ P) {
    const int t = threadIdx.x;
    if (blockIdx.x < 256) {                   // ---- gemm_p path ----
        __shared__ float Xs[32][68];          // 32 rows x 64-k chunk, padded
        const int i0 = blockIdx.x * 32;
        const int rg = t >> 6, cpair = t & 63, c0 = cpair * 2;
        float acc[8][2] = {};
        for (int kc = 0; kc < 512; kc += 64) {
            #pragma unroll
            for (int m = 0; m < 2; ++m) {
                int f = t + 256 * m;          // 0..511 float4 slots (32*64/4)
                int row = f >> 4, q = f & 15;
                *(float4*)&Xs[row][q * 4] = *(const float4*)&X[(size_t)(i0 + row) * 512 + kc + q * 4];
            }
            __syncthreads();
            #pragma unroll 4
            for (int k4 = 0; k4 < 16; ++k4) {
                float4 wA = *(const float4*)&WcT[(size_t)c0 * 512 + kc + k4 * 4];
                float4 wB = *(const float4*)&WcT[(size_t)(c0 + 1) * 512 + kc + k4 * 4];
                #pragma unroll
                for (int r = 0; r < 8; ++r) {
                    float4 x = *(const float4*)&Xs[rg * 8 + r][k4 * 4];
                    acc[r][0] += x.x * wA.x + x.y * wA.y + x.z * wA.z + x.w * wA.w;
                    acc[r][1] += x.x * wB.x + x.y * wB.y + x.z * wB.z + x.w * wB.w;
                }
            }
            __syncthreads();
        }
        #pragma unroll
        for (int r = 0; r < 8; ++r) {
            float2 v = make_float2(acc[r][0], acc[r][1]);
            *(float2*)&P[(size_t)(i0 + rg * 8 + r) * 128 + c0] = v;
        }
        return;
    }
    // ---- scan path: 256 threads x 32 elements ----
    __shared__ int part[256];
    const int base = t * 32;
    int incl[32];
    int s = 0;
    #pragma unroll
    for (int j4 = 0; j4 < 8; ++j4) {
        int4 d = *(const int4*)&deg[base + j4 * 4];
        s += d.x; incl[j4 * 4 + 0] = s;
        s += d.y; incl[j4 * 4 + 1] = s;
        s += d.z; incl[j4 * 4 + 2] = s;
        s += d.w; incl[j4 * 4 + 3] = s;
    }
    part[t] = s;
    __syncthreads();
    for (int off = 1; off < 256; off <<= 1) {
        int x = (t >= off) ? part[t - off] : 0;
        __syncthreads();
        part[t] += x;
        __syncthreads();
    }
    int excl = part[t] - s;
    if (t == 0) rowptr[0] = 0;
    #pragma unroll
    for (int j = 0; j < 32; ++j) rowptr[base + j + 1] = excl + incl[j];
}

__global__ __launch_bounds__(256) void k_fill(const int* __restrict__ src, const int* __restrict__ dst,
                                              const float* __restrict__ ew, const int* __restrict__ rowptr,
                                              int* __restrict__ cursor, int* __restrict__ srcs,
                                              float* __restrict__ wsorted) {
    int e = blockIdx.x * 256 + threadIdx.x;
    int d = dst[e];
    int p = rowptr[d] + atomicAdd(&cursor[d], 1);
    srcs[p] = src[e];
    wsorted[p] = ew[e];
}

// ---------------- aggregate: Out[d] = sum_{e: dst=d} In[src(e)] * w(e); optional Z epilogue ----------------
__global__ __launch_bounds__(128) void k_agg(const float* __restrict__ In, const int* __restrict__ rowptr,
                                             const int* __restrict__ srcs, const float* __restrict__ wsorted,
                                             float* __restrict__ Out, const float* __restrict__ noise,
                                             float* __restrict__ Z, int zpass) {
    const int b = blockIdx.x, t = threadIdx.x;
    const int beg = rowptr[b], end = rowptr[b + 1];
    float a0 = 0.f, a1 = 0.f, a2 = 0.f, a3 = 0.f;
    int i = beg;
    for (; i + 4 <= end; i += 4) {
        int   s0 = srcs[i],     s1 = srcs[i + 1], s2 = srcs[i + 2], s3 = srcs[i + 3];
        float w0 = wsorted[i],  w1 = wsorted[i + 1], w2 = wsorted[i + 2], w3 = wsorted[i + 3];
        a0 += In[(size_t)s0 * C2 + t] * w0;
        a1 += In[(size_t)s1 * C2 + t] * w1;
        a2 += In[(size_t)s2 * C2 + t] * w2;
        a3 += In[(size_t)s3 * C2 + t] * w3;
    }
    for (; i < end; ++i)
        a0 += In[(size_t)srcs[i] * C2 + t] * wsorted[i];
    float acc = (a0 + a1) + (a2 + a3);
    if (!zpass) {
        Out[(size_t)b * C2 + t] = acc;
    } else {
        __shared__ float u[C2];
        u[t] = acc;
        __syncthreads();
        if (t < 64) {
            float m = fmaxf(u[t], 0.f);
            float l = fmaxf(u[t + 64], 0.f);
            // clamp so Z is finite and a 64-term dot cannot exceed FLT_MAX:
            // |z| <= 1e18 -> |dot| <= 64 * 1e36 = 6.4e37 < 3.4e38
            float z = noise[(size_t)b * 64 + t] * expf(fminf(l, 80.f)) + m;
            z = fminf(fmaxf(z, -1e18f), 1e18f);
            Z[(size_t)b * 64 + t] = z;
        }
    }
}

// ---------------- out = Z @ Z^T  [8192 x 8192], R1-proven form: 64x64 tiles, both-LDS, LDS mirror ----------------
__global__ __launch_bounds__(256) void k_zzt(const float* __restrict__ Z, float* __restrict__ out) {
    // upper triangle of 64x64 tiles only: j0 >= i0
    if (blockIdx.x < blockIdx.y) return;
    __shared__ float Ta[64][68];              // Zi transposed: [k][row]
    __shared__ float Tb[64][68];              // Zj transposed: [k][col]
    const int t = threadIdx.x;
    const int i0 = blockIdx.y * 64, j0 = blockIdx.x * 64;
    #pragma unroll
    for (int m = 0; m < 4; ++m) {
        int f = t + 256 * m;                  // 0..1023 float4 slots (64 rows * 16)
        int row = f >> 4, q = f & 15;
        float4 va = *(const float4*)&Z[(size_t)(i0 + row) * 64 + q * 4];
        float4 vb = *(const float4*)&Z[(size_t)(j0 + row) * 64 + q * 4];
        int k = q * 4;
        Ta[k + 0][row] = va.x; Ta[k + 1][row] = va.y; Ta[k + 2][row] = va.z; Ta[k + 3][row] = va.w;
        Tb[k + 0][row] = vb.x; Tb[k + 1][row] = vb.y; Tb[k + 2][row] = vb.z; Tb[k + 3][row] = vb.w;
    }
    __syncthreads();
    const int tx = t & 15, ty = t >> 4;
    float acc[4][4] = {};
    #pragma unroll 8
    for (int k = 0; k < 64; ++k) {
        float4 a = *(const float4*)&Ta[k][ty * 4];
        float4 b = *(const float4*)&Tb[k][tx * 4];
        acc[0][0] += a.x * b.x; acc[0][1] += a.x * b.y; acc[0][2] += a.x * b.z; acc[0][3] += a.x * b.w;
        acc[1][0] += a.y * b.x; acc[1][1] += a.y * b.y; acc[1][2] += a.y * b.z; acc[1][3] += a.y * b.w;
        acc[2][0] += a.z * b.x; acc[2][1] += a.z * b.y; acc[2][2] += a.z * b.z; acc[2][3] += a.z * b.w;
        acc[3][0] += a.w * b.x; acc[3][1] += a.w * b.y; acc[3][2] += a.w * b.z; acc[3][3] += a.w * b.w;
    }
    // direct tile (i0, j0) — coalesced float4 rows
    #pragma unroll
    for (int r = 0; r < 4; ++r) {
        float4 v = make_float4(acc[r][0], acc[r][1], acc[r][2], acc[r][3]);
        *(float4*)&out[(size_t)(i0 + ty * 4 + r) * N_NODES + j0 + tx * 4] = v;
    }
    // mirrored tile (j0, i0): transpose through LDS so the global write stays coalesced
    if (i0 != j0) {
        __syncthreads();                      // done reading Ta/Tb in main loop
        #pragma unroll
        for (int r = 0; r < 4; ++r)
            #pragma unroll
            for (int c = 0; c < 4; ++c)
                Ta[tx * 4 + c][ty * 4 + r] = acc[r][c];   // Ta[col][row] = tile^T
        __syncthreads();
        #pragma unroll
        for (int m = 0; m < 4; ++m) {
            int f = t + 256 * m;              // 0..1023 float4 slots
            int row = f >> 4, q = f & 15;
            float4 v = *(const float4*)&Ta[row][q * 4];
            *(float4*)&out[(size_t)(j0 + row) * N_NODES + i0 + q * 4] = v;
        }
    }
}

extern "C" void kernel_launch(void* const* d_in, const int* in_sizes, int n_in,
                              void* d_out, int out_size, void* d_ws, size_t ws_size,
                              hipStream_t stream) {
    const float* X     = (const float*)d_in[0];
    const int*   ei    = (const int*)d_in[1];
    const float* ew    = (const float*)d_in[2];
    const float* W0    = (const float*)d_in[3];
    const float* Wm    = (const float*)d_in[4];
    const float* Wl    = (const float*)d_in[5];
    const float* noise = (const float*)d_in[6];
    float* out = (float*)d_out;

    const int* srcI = ei;                 // edge_index[0]
    const int* dstI = ei + N_EDGES;       // edge_index[1]

    // workspace layout, all in d_ws (~12.9 MB)
    int*   deg     = (int*)d_ws;                          // 8192
    int*   cursor  = deg + 8192;                          // 8192
    int*   rowptr  = deg + 16384;                         // 8193 (pad to 24592)
    int*   srcs    = deg + 24592;                         // E
    float* wsorted = (float*)(deg + 24592 + N_EDGES);     // E
    float* WcT     = wsorted + N_EDGES;                   // 128*512
    float* P       = WcT + 128 * 512;                     // 8192*128
    float* U1      = P + (size_t)N_NODES * C2;            // 8192*128
    float* Z       = U1 + (size_t)N_NODES * C2;           // 8192*64

    hipMemsetAsync(deg, 0, 16384 * sizeof(int), stream);  // deg + cursor

    k_count_wc<<<1024 + 32, 256, 0, stream>>>(dstI, deg, W0, Wm, Wl, WcT);
    k_scan_gemm<<<256 + 1, 256, 0, stream>>>(deg, rowptr, X, WcT, P);
    k_fill<<<N_EDGES / 256, 256, 0, stream>>>(srcI, dstI, ew, rowptr, cursor, srcs, wsorted);
    k_agg<<<N_NODES, 128, 0, stream>>>(P, rowptr, srcs, wsorted, U1, nullptr, nullptr, 0);
    k_agg<<<N_NODES, 128, 0, stream>>>(U1, rowptr, srcs, wsorted, nullptr, noise, Z, 1);
    k_zzt<<<dim3(N_NODES / 64, N_NODES / 64), 256, 0, stream>>>(Z, out);
}